// Round 2
// baseline (370.942 us; speedup 1.0000x reference)
//
#include <hip/hip_runtime.h>
#include <math.h>

// Problem constants (fixed by the reference)
#define BB    4
#define TT    1024
#define EE    1024
#define HH    16
#define HDIM  64
#define SS    2048            // T * MULT
#define MROWS 4096            // B * T
// Q scale with log2(e) folded in: softmax runs in exp2 domain.
#define QSCALE 0.18033688011112f   // 0.125 * log2(e)
#define LOG2E  1.4426950408889634f

typedef short  s8v  __attribute__((ext_vector_type(8)));   // 8 bf16 (4 VGPRs)
typedef float  f4v  __attribute__((ext_vector_type(4)));   // 4 fp32 acc

__device__ __forceinline__ unsigned short f2bf(float f) {
    union { float f; unsigned u; } c; c.f = f;
    unsigned u = c.u + 0x7FFFu + ((c.u >> 16) & 1u);   // RNE
    return (unsigned short)(u >> 16);
}
__device__ __forceinline__ float bflo(unsigned u) {
    union { unsigned u; float f; } c; c.u = u << 16; return c.f;
}
__device__ __forceinline__ float bfhi(unsigned u) {
    union { unsigned u; float f; } c; c.u = u & 0xffff0000u; return c.f;
}

// async global->LDS, 16B per lane. LDS dest = wave-uniform base + lane*16.
__device__ __forceinline__ void async16(const void* g, void* l) {
    __builtin_amdgcn_global_load_lds(
        (const __attribute__((address_space(1))) unsigned int*)g,
        (__attribute__((address_space(3))) unsigned int*)l,
        16, 0, 0);
}

// ---------------------------------------------------------------------------
// Fused fp32->bf16 convert: x, Wq, Wk, Wv, Wo, mask in one launch.
// Mask is additionally scaled by log2(e) (softmax runs in exp2 domain).
// ---------------------------------------------------------------------------
__global__ __launch_bounds__(256) void cvt6_kernel(
    const float* __restrict__ x,  const float* __restrict__ wq,
    const float* __restrict__ wk, const float* __restrict__ wv,
    const float* __restrict__ wo, const float* __restrict__ mk,
    unsigned short* __restrict__ xb,  unsigned short* __restrict__ wqb,
    unsigned short* __restrict__ wkb, unsigned short* __restrict__ wvb,
    unsigned short* __restrict__ wob, unsigned short* __restrict__ mbb)
{
    const int total = 3670016;
    int i = blockIdx.x * 256 + threadIdx.x;
    const int stride = gridDim.x * 256;
    for (; i < total; i += stride) {
        const float* s; unsigned short* d; int off; float sc = 1.0f;
        if (i < 1048576)      { s = x;  d = xb;  off = i; }
        else if (i < 1310720) { s = wq; d = wqb; off = i - 1048576; }
        else if (i < 1835008) { s = wk; d = wkb; off = i - 1310720; }
        else if (i < 2359296) { s = wv; d = wvb; off = i - 1835008; }
        else if (i < 2621440) { s = wo; d = wob; off = i - 2359296; }
        else                  { s = mk; d = mbb; off = i - 2621440; sc = LOG2E; }
        float4 v = ((const float4*)s)[off];
        ushort4 o;
        o.x = f2bf(v.x * sc); o.y = f2bf(v.y * sc);
        o.z = f2bf(v.z * sc); o.w = f2bf(v.w * sc);
        ((ushort4*)d)[off] = o;
    }
}

// ---------------------------------------------------------------------------
// Shared GEMM K-loop body (m97-style): 128x128 tile, BK=32, global_load_lds
// width=16 into unpadded LDS [128][32] ushort (64B rows), 2 barriers/iter.
// ---------------------------------------------------------------------------
#define GEMM_KLOOP(Aptr, Wptr, Ksz)                                            \
    for (int k0 = 0; k0 < (Ksz); k0 += 32) {                                   \
        _Pragma("unroll")                                                      \
        for (int it = 0; it < 2; ++it) {                                       \
            int f = (it * 4 + w) * 64 + lane;                                  \
            int r = f >> 2, g = (f & 3) * 8;                                   \
            async16((Aptr) + (size_t)(m0 + r) * (Ksz) + k0 + g,                \
                    As + (it * 4 + w) * 512);                                  \
            async16((Wptr) + (size_t)(n0 + r) * (Ksz) + k0 + g,                \
                    Bs + (it * 4 + w) * 512);                                  \
        }                                                                      \
        __syncthreads();                                                       \
        s8v af[4], bf[4];                                                      \
        _Pragma("unroll")                                                      \
        for (int i = 0; i < 4; ++i)                                            \
            af[i] = *(const s8v*)(As + (wm + i * 16 + col16) * 32 + quad * 8); \
        _Pragma("unroll")                                                      \
        for (int j = 0; j < 4; ++j)                                            \
            bf[j] = *(const s8v*)(Bs + (wn + j * 16 + col16) * 32 + quad * 8); \
        _Pragma("unroll")                                                      \
        for (int i = 0; i < 4; ++i)                                            \
            _Pragma("unroll")                                                  \
            for (int j = 0; j < 4; ++j)                                        \
                acc[i][j] = __builtin_amdgcn_mfma_f32_16x16x32_bf16(           \
                    af[i], bf[j], acc[i][j], 0, 0, 0);                         \
        __syncthreads();                                                       \
    }

// ---------------------------------------------------------------------------
// Fused Q+K projection: A=x [4096,1024]; blockIdx.y<8 -> Q (scale by
// SCALE*log2e, bf16 into qp), else -> K (head layout into kp). Grid (32, 24).
// ---------------------------------------------------------------------------
__global__ __launch_bounds__(256, 3) void gemm_qk_kernel(
    const unsigned short* __restrict__ X,  const unsigned short* __restrict__ Wq,
    const unsigned short* __restrict__ Wk, const float* __restrict__ bq,
    const float* __restrict__ bk, unsigned short* __restrict__ qp,
    unsigned short* __restrict__ kp)
{
    __shared__ __align__(16) unsigned short As[128 * 32];
    __shared__ __align__(16) unsigned short Bs[128 * 32];

    const int tid = threadIdx.x;
    const int lane = tid & 63, w = tid >> 6;
    const int wm = (w & 1) * 64, wn = (w >> 1) * 64;
    const int col16 = lane & 15, quad = lane >> 4;
    const int m0 = blockIdx.x * 128;
    const bool isQ = blockIdx.y < 8;
    const int n0 = blockIdx.y * 128;
    const unsigned short* Wrow = isQ ? Wq + (size_t)n0 * EE
                                     : Wk + (size_t)(n0 - EE) * EE;

    f4v acc[4][4];
#pragma unroll
    for (int i = 0; i < 4; ++i)
#pragma unroll
        for (int j = 0; j < 4; ++j) acc[i][j] = (f4v)0.0f;

    for (int k0 = 0; k0 < EE; k0 += 32) {
#pragma unroll
        for (int it = 0; it < 2; ++it) {
            int f = (it * 4 + w) * 64 + lane;
            int r = f >> 2, g = (f & 3) * 8;
            async16(X + (size_t)(m0 + r) * EE + k0 + g, As + (it * 4 + w) * 512);
            async16(Wrow + (size_t)r * EE + k0 + g, Bs + (it * 4 + w) * 512);
        }
        __syncthreads();
        s8v af[4], bf[4];
#pragma unroll
        for (int i = 0; i < 4; ++i)
            af[i] = *(const s8v*)(As + (wm + i * 16 + col16) * 32 + quad * 8);
#pragma unroll
        for (int j = 0; j < 4; ++j)
            bf[j] = *(const s8v*)(Bs + (wn + j * 16 + col16) * 32 + quad * 8);
#pragma unroll
        for (int i = 0; i < 4; ++i)
#pragma unroll
            for (int j = 0; j < 4; ++j)
                acc[i][j] = __builtin_amdgcn_mfma_f32_16x16x32_bf16(
                    af[i], bf[j], acc[i][j], 0, 0, 0);
        __syncthreads();
    }

#pragma unroll
    for (int j = 0; j < 4; ++j) {
        const int n = n0 + wn + j * 16 + col16;           // global n in [0,3072)
        const float bn = isQ ? bq[n] : bk[n - EE];
#pragma unroll
        for (int i = 0; i < 4; ++i) {
            const int mb = m0 + wm + i * 16 + quad * 4;
#pragma unroll
            for (int r = 0; r < 4; ++r) {
                const int m = mb + r;
                float c = acc[i][j][r] + bn;
                if (isQ) {
                    qp[(size_t)m * EE + n] = f2bf(c * QSCALE);
                } else {
                    const int nk = n - EE;
                    const int mm = nk >> 10, h = (nk >> 6) & 15, d = nk & 63;
                    const int b_ = m >> 10, t = m & 1023;
                    const int s = 2 * t + mm;
                    kp[((size_t)(b_ * HH + h) * SS + s) * HDIM + d] = f2bf(c);
                }
            }
        }
    }
}

// ---------------------------------------------------------------------------
// General GEMM C = alpha*(A @ W^T + bias):
//   LAYOUT 0: plain C[m*Nsz+n] (OUTF32 picks fp32/bf16)
//   LAYOUT 2: V^T: A=Wv (rows f), W=x (rows token); writes [B,H,HD,S] bf16,
//             bias indexed by row m (=f).
// ---------------------------------------------------------------------------
template <int LAYOUT, int OUTF32, int Ksz, int Nsz>
__global__ __launch_bounds__(256, 3) void gemm_mfma_kernel(
    const unsigned short* __restrict__ A, const unsigned short* __restrict__ W,
    const float* __restrict__ bias, void* __restrict__ Cout, float alpha)
{
    __shared__ __align__(16) unsigned short As[128 * 32];
    __shared__ __align__(16) unsigned short Bs[128 * 32];

    const int tid = threadIdx.x;
    const int lane = tid & 63, w = tid >> 6;
    const int wm = (w & 1) * 64, wn = (w >> 1) * 64;
    const int col16 = lane & 15, quad = lane >> 4;
    const int m0 = blockIdx.x * 128;
    const int n0 = blockIdx.y * 128;

    f4v acc[4][4];
#pragma unroll
    for (int i = 0; i < 4; ++i)
#pragma unroll
        for (int j = 0; j < 4; ++j) acc[i][j] = (f4v)0.0f;

    GEMM_KLOOP(A, W, Ksz)

#pragma unroll
    for (int j = 0; j < 4; ++j) {
        const int n = n0 + wn + j * 16 + col16;
        const float bn = (LAYOUT == 2) ? 0.0f : bias[n];
#pragma unroll
        for (int i = 0; i < 4; ++i) {
            const int mb = m0 + wm + i * 16 + quad * 4;
#pragma unroll
            for (int r = 0; r < 4; ++r) {
                const int m = mb + r;
                float c = (acc[i][j][r] + ((LAYOUT == 2) ? bias[m] : bn)) * alpha;
                if (LAYOUT == 0) {
                    if (OUTF32) ((float*)Cout)[(size_t)m * Nsz + n] = c;
                    else ((unsigned short*)Cout)[(size_t)m * Nsz + n] = f2bf(c);
                } else {  // LAYOUT 2: m = feature f, n = token
                    const int mm = m >> 10, h = (m >> 6) & 15, d = m & 63;
                    const int b_ = n >> 10, t = n & 1023;
                    const int s = 2 * t + mm;
                    ((unsigned short*)Cout)[((size_t)(b_ * HH + h) * HDIM + d) * SS + s] = f2bf(c);
                }
            }
        }
    }
}

// ---------------------------------------------------------------------------
// Flash attention v4: v3 + T14 async-STAGE (prefetch next K/V+mask tile into
// registers during current tile's compute; only ds_writes remain between
// barriers A and B), barrier D removed (P rows are wave-private; in-wave
// lgkmcnt ordering suffices), and s_setprio(1) around both MFMA clusters.
// 3 barriers/iter. LDS 34.8 KB -> 4 blocks/CU, grid 1024 fully resident.
// ---------------------------------------------------------------------------
__global__ __launch_bounds__(256, 4) void attn_mfma4_kernel(
    const unsigned short* __restrict__ Q, const unsigned short* __restrict__ Kh,
    const unsigned short* __restrict__ Vt, const unsigned short* __restrict__ Mb,
    unsigned short* __restrict__ O)
{
    constexpr int PT = 68;   // 136B pitch: conflict-free b128/b64 patterns
    __shared__ __align__(16) unsigned short K0[64 * PT];  // K half0, then P0
    __shared__ __align__(16) unsigned short K1[64 * PT];  // K half1, then P1
    __shared__ __align__(16) unsigned short V0[64 * PT];  // V^T half0 [d][s]
    __shared__ __align__(16) unsigned short V1[64 * PT];  // V^T half1 [d][s]

    const int tid = threadIdx.x;
    const int lane = tid & 63, w = tid >> 6;
    const int col16 = lane & 15, quad = lane >> 4;

    // XCD swizzle: v = gid&7 (virtual XCD), bh = v*8 + (j>>4), t0 = (j&15)*64
    const int gid = blockIdx.x;
    const int v = gid & 7, j = gid >> 3;
    const int bh = v * 8 + (j >> 4);
    const int t0 = (j & 15) * 64;
    const int b_ = bh >> 4, h = bh & 15;

    // Q fragments in registers: this lane's t-row = w*16+col16, k-slices
    const unsigned short* Qrow =
        Q + (size_t)(b_ * TT + t0 + w * 16 + col16) * EE + h * HDIM;
    const s8v qf0 = *(const s8v*)(Qrow + quad * 8);
    const s8v qf1 = *(const s8v*)(Qrow + 32 + quad * 8);

    f4v oacc[4];
#pragma unroll
    for (int jd = 0; jd < 4; ++jd) oacc[jd] = (f4v)0.0f;
    float mrun = -INFINITY;
    f4v l4 = (f4v)0.0f;           // per-lane partial row-sum (4 s-slots)

    const unsigned short* Kb   = Kh + (size_t)bh * SS * HDIM;
    const unsigned short* Vb   = Vt + (size_t)bh * HDIM * SS;
    const unsigned short* Mrow = Mb + (size_t)b_ * TT * TT
                               + (size_t)(t0 + w * 16 + col16) * TT;
    const int myrow = (w * 16 + col16) * PT;   // this lane's t-row in LDS
    const int r0 = tid >> 3, c0 = (tid & 7) * 8;   // staging row/col (st=0)

    // T14: staged K/V tile in registers (32 VGPR) + next-iter mask
    uint4 kv[8];
    uint2 mmc[4];

#define PREF_KV(T2B)                                                           \
    kv[0] = *(const uint4*)(Kb + (size_t)((T2B) + r0) * HDIM + c0);            \
    kv[1] = *(const uint4*)(Kb + (size_t)((T2B) + r0 + 32) * HDIM + c0);       \
    kv[2] = *(const uint4*)(Kb + (size_t)(1024 + (T2B) + r0) * HDIM + c0);     \
    kv[3] = *(const uint4*)(Kb + (size_t)(1024 + (T2B) + r0 + 32) * HDIM + c0);\
    kv[4] = *(const uint4*)(Vb + (size_t)r0 * SS + (T2B) + c0);                \
    kv[5] = *(const uint4*)(Vb + (size_t)(r0 + 32) * SS + (T2B) + c0);         \
    kv[6] = *(const uint4*)(Vb + (size_t)r0 * SS + 1024 + (T2B) + c0);         \
    kv[7] = *(const uint4*)(Vb + (size_t)(r0 + 32) * SS + 1024 + (T2B) + c0);

    // prologue: tile 0
    PREF_KV(0)
#pragma unroll
    for (int js = 0; js < 4; ++js)
        mmc[js] = *(const uint2*)(Mrow + js * 16 + quad * 4);

    for (int it16 = 0; it16 < 16; ++it16) {
        __syncthreads();  // (A) prev iteration's PV reads done

        // write staged tile (regs -> LDS); loads completed during prev compute
        *(uint4*)(K0 + r0 * PT + c0)        = kv[0];
        *(uint4*)(K0 + (r0 + 32) * PT + c0) = kv[1];
        *(uint4*)(K1 + r0 * PT + c0)        = kv[2];
        *(uint4*)(K1 + (r0 + 32) * PT + c0) = kv[3];
        *(uint4*)(V0 + r0 * PT + c0)        = kv[4];
        *(uint4*)(V0 + (r0 + 32) * PT + c0) = kv[5];
        *(uint4*)(V1 + r0 * PT + c0)        = kv[6];
        *(uint4*)(V1 + (r0 + 32) * PT + c0) = kv[7];
        __syncthreads();  // (B)

        // S-acc init from current mask regs (mask folded into MFMA C-operand)
        f4v s0acc[4], s1acc[4];
#pragma unroll
        for (int js = 0; js < 4; ++js) {
            f4v mv;
            mv[0] = bflo(mmc[js].x); mv[1] = bfhi(mmc[js].x);
            mv[2] = bflo(mmc[js].y); mv[3] = bfhi(mmc[js].y);
            s0acc[js] = mv; s1acc[js] = mv;
        }

        // T14: prefetch next tile (clamped wrap; results land during compute)
        {
            const int t2n = ((it16 + 1) & 15) * 64;
            PREF_KV(t2n)
#pragma unroll
            for (int js = 0; js < 4; ++js)
                mmc[js] = *(const uint2*)(Mrow + t2n + js * 16 + quad * 4);
        }

        // S^T halves: A=K (m=s), B=Q (n=t)
        __builtin_amdgcn_s_setprio(1);
#pragma unroll
        for (int ks = 0; ks < 2; ++ks) {
            const s8v bq_ = ks ? qf1 : qf0;
#pragma unroll
            for (int js = 0; js < 4; ++js) {
                s8v ak0 = *(const s8v*)(K0 + (js * 16 + col16) * PT + ks * 32 + quad * 8);
                s8v ak1 = *(const s8v*)(K1 + (js * 16 + col16) * PT + ks * 32 + quad * 8);
                s0acc[js] = __builtin_amdgcn_mfma_f32_16x16x32_bf16(ak0, bq_, s0acc[js], 0, 0, 0);
                s1acc[js] = __builtin_amdgcn_mfma_f32_16x16x32_bf16(ak1, bq_, s1acc[js], 0, 0, 0);
            }
        }
        __builtin_amdgcn_s_setprio(0);

        // per-lane max over this lane's 32 S values
        float tm0 = fmaxf(fmaxf(s0acc[0][0], s0acc[0][1]), fmaxf(s0acc[0][2], s0acc[0][3]));
        float tm1 = fmaxf(fmaxf(s0acc[1][0], s0acc[1][1]), fmaxf(s0acc[1][2], s0acc[1][3]));
        float tm2 = fmaxf(fmaxf(s0acc[2][0], s0acc[2][1]), fmaxf(s0acc[2][2], s0acc[2][3]));
        float tm3 = fmaxf(fmaxf(s0acc[3][0], s0acc[3][1]), fmaxf(s0acc[3][2], s0acc[3][3]));
        float tn0 = fmaxf(fmaxf(s1acc[0][0], s1acc[0][1]), fmaxf(s1acc[0][2], s1acc[0][3]));
        float tn1 = fmaxf(fmaxf(s1acc[1][0], s1acc[1][1]), fmaxf(s1acc[1][2], s1acc[1][3]));
        float tn2 = fmaxf(fmaxf(s1acc[2][0], s1acc[2][1]), fmaxf(s1acc[2][2], s1acc[2][3]));
        float tn3 = fmaxf(fmaxf(s1acc[3][0], s1acc[3][1]), fmaxf(s1acc[3][2], s1acc[3][3]));
        float tmax = fmaxf(fmaxf(fmaxf(tm0, tm1), fmaxf(tm2, tm3)),
                           fmaxf(fmaxf(tn0, tn1), fmaxf(tn2, tn3)));

        // defer-max: rescale only if some lane's max grew past mrun + 10
        if (!__all(tmax - mrun <= 10.0f)) {
            float tfull = fmaxf(tmax, __shfl_xor(tmax, 16));
            tfull = fmaxf(tfull, __shfl_xor(tfull, 32));
            const float mnew = fmaxf(mrun, tfull);
            const float scl = __builtin_amdgcn_exp2f(mrun - mnew);  // 0 on 1st
            l4 *= scl;
            float sclr[4];
#pragma unroll
            for (int r = 0; r < 4; ++r) sclr[r] = __shfl(scl, quad * 4 + r);
#pragma unroll
            for (int jd = 0; jd < 4; ++jd)
#pragma unroll
                for (int r = 0; r < 4; ++r) oacc[jd][r] *= sclr[r];
            mrun = mnew;
        }

        // exp2 + pack to bf16 (pre-barrier-C; only stores go after C)
        unsigned pk0[8], pk1[8];
#pragma unroll
        for (int js = 0; js < 4; ++js) {
            f4v p0 = s0acc[js] - mrun;
            f4v p1 = s1acc[js] - mrun;
#pragma unroll
            for (int r = 0; r < 4; ++r) {
                p0[r] = __builtin_amdgcn_exp2f(p0[r]);
                p1[r] = __builtin_amdgcn_exp2f(p1[r]);
            }
            l4 += p0 + p1;
            __asm__("v_cvt_pk_bf16_f32 %0, %1, %2" : "=v"(pk0[js*2])   : "v"(p0[0]), "v"(p0[1]));
            __asm__("v_cvt_pk_bf16_f32 %0, %1, %2" : "=v"(pk0[js*2+1]) : "v"(p0[2]), "v"(p0[3]));
            __asm__("v_cvt_pk_bf16_f32 %0, %1, %2" : "=v"(pk1[js*2])   : "v"(p1[0]), "v"(p1[1]));
            __asm__("v_cvt_pk_bf16_f32 %0, %1, %2" : "=v"(pk1[js*2+1]) : "v"(p1[2]), "v"(p1[3]));
        }

        __syncthreads();  // (C) all waves done reading K0/K1

        // P store (wave-private rows) -> no barrier needed before readback:
        // same-wave same-address LDS ordering via lgkmcnt (compiler-inserted)
#pragma unroll
        for (int js = 0; js < 4; ++js) {
            *(uint2*)(K0 + myrow + js * 16 + quad * 4) = make_uint2(pk0[js*2], pk0[js*2+1]);
            *(uint2*)(K1 + myrow + js * 16 + quad * 4) = make_uint2(pk1[js*2], pk1[js*2+1]);
        }

        // O += P0.V0 + P1.V1 : A[m=t][k=s] from K0/K1, B[n=d][k=s] from V0/V1
        __builtin_amdgcn_s_setprio(1);
#pragma unroll
        for (int ks = 0; ks < 2; ++ks) {
            s8v p0 = *(const s8v*)(K0 + myrow + ks * 32 + quad * 8);
            s8v p1 = *(const s8v*)(K1 + myrow + ks * 32 + quad * 8);
#pragma unroll
            for (int jd = 0; jd < 4; ++jd) {
                s8v v0_ = *(const s8v*)(V0 + (jd * 16 + col16) * PT + ks * 32 + quad * 8);
                s8v v1_ = *(const s8v*)(V1 + (jd * 16 + col16) * PT + ks * 32 + quad * 8);
                oacc[jd] = __builtin_amdgcn_mfma_f32_16x16x32_bf16(p0, v0_, oacc[jd], 0, 0, 0);
                oacc[jd] = __builtin_amdgcn_mfma_f32_16x16x32_bf16(p1, v1_, oacc[jd], 0, 0, 0);
            }
        }
        __builtin_amdgcn_s_setprio(0);
    }
#undef PREF_KV

    // epilogue: reduce row-sum partials (4 s-slots, then cross-quad),
    // normalize and write bf16
    float lr = l4[0] + l4[1] + l4[2] + l4[3];
    lr += __shfl_xor(lr, 16);
    lr += __shfl_xor(lr, 32);
    const float inv = 1.0f / lr;
    float invr[4];
#pragma unroll
    for (int r = 0; r < 4; ++r) invr[r] = __shfl(inv, quad * 4 + r);
#pragma unroll
    for (int r = 0; r < 4; ++r) {
        const int t = t0 + w * 16 + quad * 4 + r;
#pragma unroll
        for (int jd = 0; jd < 4; ++jd)
            O[(size_t)(b_ * TT + t) * EE + h * HDIM + jd * 16 + col16] =
                f2bf(oacc[jd][r] * invr[r]);
    }
}

// ---------------------------------------------------------------------------
extern "C" void kernel_launch(void* const* d_in, const int* in_sizes, int n_in,
                              void* d_out, int out_size, void* d_ws, size_t ws_size,
                              hipStream_t stream)
{
    (void)in_sizes; (void)n_in; (void)out_size; (void)ws_size;

    const float* x    = (const float*)d_in[0];
    const float* mask = (const float*)d_in[1];
    const float* Wq   = (const float*)d_in[2];
    const float* bq   = (const float*)d_in[3];
    const float* Wk   = (const float*)d_in[4];
    const float* bk   = (const float*)d_in[5];
    const float* Wv   = (const float*)d_in[6];
    const float* bv   = (const float*)d_in[7];
    const float* Wo   = (const float*)d_in[8];
    const float* bo   = (const float*)d_in[9];
    float* out = (float*)d_out;

    // workspace carve (ushort units): 42M ushorts = 84 MB
    unsigned short* xb  = (unsigned short*)d_ws;
    unsigned short* wqb = xb  + (size_t)MROWS * EE;          // 4M
    unsigned short* wkb = wqb + (size_t)EE * EE;             // 1M
    unsigned short* wvb = wkb + (size_t)2 * EE * EE;         // 2M
    unsigned short* wob = wvb + (size_t)2 * EE * EE;         // 2M
    unsigned short* mb  = wob + (size_t)EE * EE;             // 1M
    unsigned short* qp  = mb  + (size_t)BB * TT * TT;        // 4M
    unsigned short* kp  = qp  + (size_t)MROWS * EE;          // 4M
    unsigned short* vt  = kp  + (size_t)BB * HH * SS * HDIM; // 8M
    unsigned short* ao  = vt  + (size_t)BB * HH * SS * HDIM; // 8M

    dim3 blk(256);

    // fused fp32->bf16 conversion (x + 4 weights + mask; mask *= log2e)
    cvt6_kernel<<<4096, blk, 0, stream>>>(x, Wq, Wk, Wv, Wo, mask,
                                          xb, wqb, wkb, wvb, wob, mb);
    // fused Q+K projection (Q scaled by SCALE*log2e for exp2-domain softmax)
    gemm_qk_kernel<<<dim3(32, 24), blk, 0, stream>>>(xb, wqb, wkb, bq, bk, qp, kp);
    // V projection computed transposed (A=Wv, W=x) -> V^T [B,H,HD,S]
    gemm_mfma_kernel<2, 0, EE, MROWS><<<dim3(16, 32), blk, 0, stream>>>(
        wvb, xb, bv, vt, 1.0f);
    // attention (T14 async-stage, 3 barriers/iter, setprio, 4 blocks/CU)
    attn_mfma4_kernel<<<dim3(1024), blk, 0, stream>>>(qp, kp, vt, mb, ao);
    // output projection -> fp32 out
    gemm_mfma_kernel<0, 1, EE, EE><<<dim3(32, 8), blk, 0, stream>>>(
        ao, wob, bo, out, 1.0f);
}

// Round 3
// 258.530 us; speedup vs baseline: 1.4348x; 1.4348x over previous
//
#include <hip/hip_runtime.h>
#include <math.h>

// Problem constants (fixed by the reference)
#define BB    4
#define TT    1024
#define EE    1024
#define HH    16
#define HDIM  64
#define SS    2048            // T * MULT
#define MROWS 4096            // B * T
// Q scale with log2(e) folded in: softmax runs in exp2 domain.
#define QSCALE 0.18033688011112f   // 0.125 * log2(e)
#define LOG2E  1.4426950408889634f

typedef short  s8v  __attribute__((ext_vector_type(8)));   // 8 bf16 (4 VGPRs)
typedef float  f4v  __attribute__((ext_vector_type(4)));   // 4 fp32 acc

__device__ __forceinline__ unsigned short f2bf(float f) {
    union { float f; unsigned u; } c; c.f = f;
    unsigned u = c.u + 0x7FFFu + ((c.u >> 16) & 1u);   // RNE
    return (unsigned short)(u >> 16);
}
__device__ __forceinline__ float bflo(unsigned u) {
    union { unsigned u; float f; } c; c.u = u << 16; return c.f;
}
__device__ __forceinline__ float bfhi(unsigned u) {
    union { unsigned u; float f; } c; c.u = u & 0xffff0000u; return c.f;
}

// async global->LDS, 16B per lane. LDS dest = wave-uniform base + lane*16.
__device__ __forceinline__ void async16(const void* g, void* l) {
    __builtin_amdgcn_global_load_lds(
        (const __attribute__((address_space(1))) unsigned int*)g,
        (__attribute__((address_space(3))) unsigned int*)l,
        16, 0, 0);
}

// ---------------------------------------------------------------------------
// Fused fp32->bf16 convert: x, Wq, Wk, Wv, Wo, mask in one launch.
// Mask is additionally scaled by log2(e) (softmax runs in exp2 domain).
// ---------------------------------------------------------------------------
__global__ __launch_bounds__(256) void cvt6_kernel(
    const float* __restrict__ x,  const float* __restrict__ wq,
    const float* __restrict__ wk, const float* __restrict__ wv,
    const float* __restrict__ wo, const float* __restrict__ mk,
    unsigned short* __restrict__ xb,  unsigned short* __restrict__ wqb,
    unsigned short* __restrict__ wkb, unsigned short* __restrict__ wvb,
    unsigned short* __restrict__ wob, unsigned short* __restrict__ mbb)
{
    const int total = 3670016;
    int i = blockIdx.x * 256 + threadIdx.x;
    const int stride = gridDim.x * 256;
    for (; i < total; i += stride) {
        const float* s; unsigned short* d; int off; float sc = 1.0f;
        if (i < 1048576)      { s = x;  d = xb;  off = i; }
        else if (i < 1310720) { s = wq; d = wqb; off = i - 1048576; }
        else if (i < 1835008) { s = wk; d = wkb; off = i - 1310720; }
        else if (i < 2359296) { s = wv; d = wvb; off = i - 1835008; }
        else if (i < 2621440) { s = wo; d = wob; off = i - 2359296; }
        else                  { s = mk; d = mbb; off = i - 2621440; sc = LOG2E; }
        float4 v = ((const float4*)s)[off];
        ushort4 o;
        o.x = f2bf(v.x * sc); o.y = f2bf(v.y * sc);
        o.z = f2bf(v.z * sc); o.w = f2bf(v.w * sc);
        ((ushort4*)d)[off] = o;
    }
}

// ---------------------------------------------------------------------------
// Shared GEMM K-loop body (m97-style): 128x128 tile, BK=32, global_load_lds
// width=16 into unpadded LDS [128][32] ushort (64B rows), 2 barriers/iter.
// ---------------------------------------------------------------------------
#define GEMM_KLOOP(Aptr, Wptr, Ksz)                                            \
    for (int k0 = 0; k0 < (Ksz); k0 += 32) {                                   \
        _Pragma("unroll")                                                      \
        for (int it = 0; it < 2; ++it) {                                       \
            int f = (it * 4 + w) * 64 + lane;                                  \
            int r = f >> 2, g = (f & 3) * 8;                                   \
            async16((Aptr) + (size_t)(m0 + r) * (Ksz) + k0 + g,                \
                    As + (it * 4 + w) * 512);                                  \
            async16((Wptr) + (size_t)(n0 + r) * (Ksz) + k0 + g,                \
                    Bs + (it * 4 + w) * 512);                                  \
        }                                                                      \
        __syncthreads();                                                       \
        s8v af[4], bf[4];                                                      \
        _Pragma("unroll")                                                      \
        for (int i = 0; i < 4; ++i)                                            \
            af[i] = *(const s8v*)(As + (wm + i * 16 + col16) * 32 + quad * 8); \
        _Pragma("unroll")                                                      \
        for (int j = 0; j < 4; ++j)                                            \
            bf[j] = *(const s8v*)(Bs + (wn + j * 16 + col16) * 32 + quad * 8); \
        _Pragma("unroll")                                                      \
        for (int i = 0; i < 4; ++i)                                            \
            _Pragma("unroll")                                                  \
            for (int j = 0; j < 4; ++j)                                        \
                acc[i][j] = __builtin_amdgcn_mfma_f32_16x16x32_bf16(           \
                    af[i], bf[j], acc[i][j], 0, 0, 0);                         \
        __syncthreads();                                                       \
    }

// ---------------------------------------------------------------------------
// Fused Q+K projection: A=x [4096,1024]; blockIdx.y<8 -> Q (scale by
// SCALE*log2e, bf16 into qp), else -> K (head layout into kp). Grid (32, 24).
// ---------------------------------------------------------------------------
__global__ __launch_bounds__(256, 3) void gemm_qk_kernel(
    const unsigned short* __restrict__ X,  const unsigned short* __restrict__ Wq,
    const unsigned short* __restrict__ Wk, const float* __restrict__ bq,
    const float* __restrict__ bk, unsigned short* __restrict__ qp,
    unsigned short* __restrict__ kp)
{
    __shared__ __align__(16) unsigned short As[128 * 32];
    __shared__ __align__(16) unsigned short Bs[128 * 32];

    const int tid = threadIdx.x;
    const int lane = tid & 63, w = tid >> 6;
    const int wm = (w & 1) * 64, wn = (w >> 1) * 64;
    const int col16 = lane & 15, quad = lane >> 4;
    const int m0 = blockIdx.x * 128;
    const bool isQ = blockIdx.y < 8;
    const int n0 = blockIdx.y * 128;
    const unsigned short* Wrow = isQ ? Wq + (size_t)n0 * EE
                                     : Wk + (size_t)(n0 - EE) * EE;

    f4v acc[4][4];
#pragma unroll
    for (int i = 0; i < 4; ++i)
#pragma unroll
        for (int j = 0; j < 4; ++j) acc[i][j] = (f4v)0.0f;

    for (int k0 = 0; k0 < EE; k0 += 32) {
#pragma unroll
        for (int it = 0; it < 2; ++it) {
            int f = (it * 4 + w) * 64 + lane;
            int r = f >> 2, g = (f & 3) * 8;
            async16(X + (size_t)(m0 + r) * EE + k0 + g, As + (it * 4 + w) * 512);
            async16(Wrow + (size_t)r * EE + k0 + g, Bs + (it * 4 + w) * 512);
        }
        __syncthreads();
        s8v af[4], bf[4];
#pragma unroll
        for (int i = 0; i < 4; ++i)
            af[i] = *(const s8v*)(As + (wm + i * 16 + col16) * 32 + quad * 8);
#pragma unroll
        for (int j = 0; j < 4; ++j)
            bf[j] = *(const s8v*)(Bs + (wn + j * 16 + col16) * 32 + quad * 8);
#pragma unroll
        for (int i = 0; i < 4; ++i)
#pragma unroll
            for (int j = 0; j < 4; ++j)
                acc[i][j] = __builtin_amdgcn_mfma_f32_16x16x32_bf16(
                    af[i], bf[j], acc[i][j], 0, 0, 0);
        __syncthreads();
    }

#pragma unroll
    for (int j = 0; j < 4; ++j) {
        const int n = n0 + wn + j * 16 + col16;           // global n in [0,3072)
        const float bn = isQ ? bq[n] : bk[n - EE];
#pragma unroll
        for (int i = 0; i < 4; ++i) {
            const int mb = m0 + wm + i * 16 + quad * 4;
#pragma unroll
            for (int r = 0; r < 4; ++r) {
                const int m = mb + r;
                float c = acc[i][j][r] + bn;
                if (isQ) {
                    qp[(size_t)m * EE + n] = f2bf(c * QSCALE);
                } else {
                    const int nk = n - EE;
                    const int mm = nk >> 10, h = (nk >> 6) & 15, d = nk & 63;
                    const int b_ = m >> 10, t = m & 1023;
                    const int s = 2 * t + mm;
                    kp[((size_t)(b_ * HH + h) * SS + s) * HDIM + d] = f2bf(c);
                }
            }
        }
    }
}

// ---------------------------------------------------------------------------
// General GEMM C = alpha*(A @ W^T + bias):
//   LAYOUT 0: plain C[m*Nsz+n] (OUTF32 picks fp32/bf16)
//   LAYOUT 2: V^T: A=Wv (rows f), W=x (rows token); writes [B,H,HD,S] bf16,
//             bias indexed by row m (=f).
// ---------------------------------------------------------------------------
template <int LAYOUT, int OUTF32, int Ksz, int Nsz>
__global__ __launch_bounds__(256, 3) void gemm_mfma_kernel(
    const unsigned short* __restrict__ A, const unsigned short* __restrict__ W,
    const float* __restrict__ bias, void* __restrict__ Cout, float alpha)
{
    __shared__ __align__(16) unsigned short As[128 * 32];
    __shared__ __align__(16) unsigned short Bs[128 * 32];

    const int tid = threadIdx.x;
    const int lane = tid & 63, w = tid >> 6;
    const int wm = (w & 1) * 64, wn = (w >> 1) * 64;
    const int col16 = lane & 15, quad = lane >> 4;
    const int m0 = blockIdx.x * 128;
    const int n0 = blockIdx.y * 128;

    f4v acc[4][4];
#pragma unroll
    for (int i = 0; i < 4; ++i)
#pragma unroll
        for (int j = 0; j < 4; ++j) acc[i][j] = (f4v)0.0f;

    GEMM_KLOOP(A, W, Ksz)

#pragma unroll
    for (int j = 0; j < 4; ++j) {
        const int n = n0 + wn + j * 16 + col16;
        const float bn = (LAYOUT == 2) ? 0.0f : bias[n];
#pragma unroll
        for (int i = 0; i < 4; ++i) {
            const int mb = m0 + wm + i * 16 + quad * 4;
#pragma unroll
            for (int r = 0; r < 4; ++r) {
                const int m = mb + r;
                float c = (acc[i][j][r] + ((LAYOUT == 2) ? bias[m] : bn)) * alpha;
                if (LAYOUT == 0) {
                    if (OUTF32) ((float*)Cout)[(size_t)m * Nsz + n] = c;
                    else ((unsigned short*)Cout)[(size_t)m * Nsz + n] = f2bf(c);
                } else {  // LAYOUT 2: m = feature f, n = token
                    const int mm = m >> 10, h = (m >> 6) & 15, d = m & 63;
                    const int b_ = n >> 10, t = n & 1023;
                    const int s = 2 * t + mm;
                    ((unsigned short*)Cout)[((size_t)(b_ * HH + h) * HDIM + d) * SS + s] = f2bf(c);
                }
            }
        }
    }
}

// ---------------------------------------------------------------------------
// Flash attention v5: v3 structure + T14 with SPLIT, STAGGERED prefetch to
// stay under the 128-VGPR cap (v4's single early prefetch spilled to scratch:
// 441 MB WRITE_SIZE).
//  - K(next)+mask(next) issued before barrier B (live across S+softmax+PV;
//    V-stage regs dead there)
//  - V(next) issued after pk pack, before barrier C (live across P-store+PV;
//    s0acc/s1acc dead there)
//  - all staged values in NAMED registers (no arrays -> no scratch demotion)
//  - barrier D removed (P rows wave-private); setprio around MFMA clusters
// LDS 34.8 KB -> 4 blocks/CU; grid 1024 fully resident in one round.
// ---------------------------------------------------------------------------
__global__ __launch_bounds__(256, 4) void attn_mfma5_kernel(
    const unsigned short* __restrict__ Q, const unsigned short* __restrict__ Kh,
    const unsigned short* __restrict__ Vt, const unsigned short* __restrict__ Mb,
    unsigned short* __restrict__ O)
{
    constexpr int PT = 68;   // 136B pitch: conflict-free b128/b64 patterns
    __shared__ __align__(16) unsigned short K0[64 * PT];  // K half0, then P0
    __shared__ __align__(16) unsigned short K1[64 * PT];  // K half1, then P1
    __shared__ __align__(16) unsigned short V0[64 * PT];  // V^T half0 [d][s]
    __shared__ __align__(16) unsigned short V1[64 * PT];  // V^T half1 [d][s]

    const int tid = threadIdx.x;
    const int lane = tid & 63, w = tid >> 6;
    const int col16 = lane & 15, quad = lane >> 4;

    // XCD swizzle: v = gid&7 (virtual XCD), bh = v*8 + (j>>4), t0 = (j&15)*64
    const int gid = blockIdx.x;
    const int v = gid & 7, j = gid >> 3;
    const int bh = v * 8 + (j >> 4);
    const int t0 = (j & 15) * 64;
    const int b_ = bh >> 4, h = bh & 15;

    // Q fragments in registers: this lane's t-row = w*16+col16, k-slices
    const unsigned short* Qrow =
        Q + (size_t)(b_ * TT + t0 + w * 16 + col16) * EE + h * HDIM;
    const s8v qf0 = *(const s8v*)(Qrow + quad * 8);
    const s8v qf1 = *(const s8v*)(Qrow + 32 + quad * 8);

    f4v oacc[4];
#pragma unroll
    for (int jd = 0; jd < 4; ++jd) oacc[jd] = (f4v)0.0f;
    float mrun = -INFINITY;
    f4v l4 = (f4v)0.0f;           // per-lane partial row-sum (4 s-slots)

    const unsigned short* Kb   = Kh + (size_t)bh * SS * HDIM;
    const unsigned short* Vb   = Vt + (size_t)bh * HDIM * SS;
    const unsigned short* Mrow = Mb + (size_t)b_ * TT * TT
                               + (size_t)(t0 + w * 16 + col16) * TT;
    const int myrow = (w * 16 + col16) * PT;   // this lane's t-row in LDS
    const int r0 = tid >> 3, c0 = (tid & 7) * 8;   // staging row/col

    // T14 staged tile: NAMED registers only (arrays risk scratch demotion)
    uint4 kA0, kA1, kB0, kB1;   // K half0/half1, rows r0 and r0+32
    uint4 vA0, vA1, vB0, vB1;   // V^T half0/half1
    uint2 mA0, mA1, mA2, mA3;   // mask cols for this lane's t-row

#define PREF_K(T2B)                                                            \
    kA0 = *(const uint4*)(Kb + (size_t)((T2B) + r0) * HDIM + c0);              \
    kA1 = *(const uint4*)(Kb + (size_t)((T2B) + r0 + 32) * HDIM + c0);         \
    kB0 = *(const uint4*)(Kb + (size_t)(1024 + (T2B) + r0) * HDIM + c0);       \
    kB1 = *(const uint4*)(Kb + (size_t)(1024 + (T2B) + r0 + 32) * HDIM + c0);
#define PREF_V(T2B)                                                            \
    vA0 = *(const uint4*)(Vb + (size_t)r0 * SS + (T2B) + c0);                  \
    vA1 = *(const uint4*)(Vb + (size_t)(r0 + 32) * SS + (T2B) + c0);           \
    vB0 = *(const uint4*)(Vb + (size_t)r0 * SS + 1024 + (T2B) + c0);           \
    vB1 = *(const uint4*)(Vb + (size_t)(r0 + 32) * SS + 1024 + (T2B) + c0);
#define PREF_M(T2B)                                                            \
    mA0 = *(const uint2*)(Mrow + (T2B) + 0 * 16 + quad * 4);                   \
    mA1 = *(const uint2*)(Mrow + (T2B) + 1 * 16 + quad * 4);                   \
    mA2 = *(const uint2*)(Mrow + (T2B) + 2 * 16 + quad * 4);                   \
    mA3 = *(const uint2*)(Mrow + (T2B) + 3 * 16 + quad * 4);

    // prologue: tile 0 fully staged
    PREF_K(0)
    PREF_V(0)
    PREF_M(0)

    for (int it16 = 0; it16 < 16; ++it16) {
        __syncthreads();  // (A) prev iteration's PV reads done

        // write staged tile (regs -> LDS); loads long since completed
        *(uint4*)(K0 + r0 * PT + c0)        = kA0;
        *(uint4*)(K0 + (r0 + 32) * PT + c0) = kA1;
        *(uint4*)(K1 + r0 * PT + c0)        = kB0;
        *(uint4*)(K1 + (r0 + 32) * PT + c0) = kB1;
        *(uint4*)(V0 + r0 * PT + c0)        = vA0;
        *(uint4*)(V0 + (r0 + 32) * PT + c0) = vA1;
        *(uint4*)(V1 + r0 * PT + c0)        = vB0;
        *(uint4*)(V1 + (r0 + 32) * PT + c0) = vB1;

        // S-acc init from current mask regs (register-only; pre-B is fine)
        f4v s0acc[4], s1acc[4];
        {
            f4v mv;
            mv[0] = bflo(mA0.x); mv[1] = bfhi(mA0.x);
            mv[2] = bflo(mA0.y); mv[3] = bfhi(mA0.y);
            s0acc[0] = mv; s1acc[0] = mv;
            mv[0] = bflo(mA1.x); mv[1] = bfhi(mA1.x);
            mv[2] = bflo(mA1.y); mv[3] = bfhi(mA1.y);
            s0acc[1] = mv; s1acc[1] = mv;
            mv[0] = bflo(mA2.x); mv[1] = bfhi(mA2.x);
            mv[2] = bflo(mA2.y); mv[3] = bfhi(mA2.y);
            s0acc[2] = mv; s1acc[2] = mv;
            mv[0] = bflo(mA3.x); mv[1] = bfhi(mA3.x);
            mv[2] = bflo(mA3.y); mv[3] = bfhi(mA3.y);
            s0acc[3] = mv; s1acc[3] = mv;
        }

        // T14a: K(next)+mask(next) in flight across the whole compute phase
        const int t2n = ((it16 + 1) & 15) * 64;
        PREF_K(t2n)
        PREF_M(t2n)

        __syncthreads();  // (B) staged tile visible to all waves

        // S^T halves: A=K (m=s), B=Q (n=t); mask pre-loaded in C-operand
        __builtin_amdgcn_s_setprio(1);
#pragma unroll
        for (int ks = 0; ks < 2; ++ks) {
            const s8v bq_ = ks ? qf1 : qf0;
#pragma unroll
            for (int js = 0; js < 4; ++js) {
                s8v ak0 = *(const s8v*)(K0 + (js * 16 + col16) * PT + ks * 32 + quad * 8);
                s8v ak1 = *(const s8v*)(K1 + (js * 16 + col16) * PT + ks * 32 + quad * 8);
                s0acc[js] = __builtin_amdgcn_mfma_f32_16x16x32_bf16(ak0, bq_, s0acc[js], 0, 0, 0);
                s1acc[js] = __builtin_amdgcn_mfma_f32_16x16x32_bf16(ak1, bq_, s1acc[js], 0, 0, 0);
            }
        }
        __builtin_amdgcn_s_setprio(0);

        // per-lane max over this lane's 32 S values
        float tm0 = fmaxf(fmaxf(s0acc[0][0], s0acc[0][1]), fmaxf(s0acc[0][2], s0acc[0][3]));
        float tm1 = fmaxf(fmaxf(s0acc[1][0], s0acc[1][1]), fmaxf(s0acc[1][2], s0acc[1][3]));
        float tm2 = fmaxf(fmaxf(s0acc[2][0], s0acc[2][1]), fmaxf(s0acc[2][2], s0acc[2][3]));
        float tm3 = fmaxf(fmaxf(s0acc[3][0], s0acc[3][1]), fmaxf(s0acc[3][2], s0acc[3][3]));
        float tn0 = fmaxf(fmaxf(s1acc[0][0], s1acc[0][1]), fmaxf(s1acc[0][2], s1acc[0][3]));
        float tn1 = fmaxf(fmaxf(s1acc[1][0], s1acc[1][1]), fmaxf(s1acc[1][2], s1acc[1][3]));
        float tn2 = fmaxf(fmaxf(s1acc[2][0], s1acc[2][1]), fmaxf(s1acc[2][2], s1acc[2][3]));
        float tn3 = fmaxf(fmaxf(s1acc[3][0], s1acc[3][1]), fmaxf(s1acc[3][2], s1acc[3][3]));
        float tmax = fmaxf(fmaxf(fmaxf(tm0, tm1), fmaxf(tm2, tm3)),
                           fmaxf(fmaxf(tn0, tn1), fmaxf(tn2, tn3)));

        // defer-max: rescale only if some lane's max grew past mrun + 10
        if (!__all(tmax - mrun <= 10.0f)) {
            float tfull = fmaxf(tmax, __shfl_xor(tmax, 16));
            tfull = fmaxf(tfull, __shfl_xor(tfull, 32));
            const float mnew = fmaxf(mrun, tfull);
            const float scl = __builtin_amdgcn_exp2f(mrun - mnew);  // 0 on 1st
            l4 *= scl;
            float sclr[4];
#pragma unroll
            for (int r = 0; r < 4; ++r) sclr[r] = __shfl(scl, quad * 4 + r);
#pragma unroll
            for (int jd = 0; jd < 4; ++jd)
#pragma unroll
                for (int r = 0; r < 4; ++r) oacc[jd][r] *= sclr[r];
            mrun = mnew;
        }

        // exp2 + pack to bf16 (pre-barrier-C; only stores go after C)
        unsigned pk0[8], pk1[8];
#pragma unroll
        for (int js = 0; js < 4; ++js) {
            f4v p0 = s0acc[js] - mrun;
            f4v p1 = s1acc[js] - mrun;
#pragma unroll
            for (int r = 0; r < 4; ++r) {
                p0[r] = __builtin_amdgcn_exp2f(p0[r]);
                p1[r] = __builtin_amdgcn_exp2f(p1[r]);
            }
            l4 += p0 + p1;
            __asm__("v_cvt_pk_bf16_f32 %0, %1, %2" : "=v"(pk0[js*2])   : "v"(p0[0]), "v"(p0[1]));
            __asm__("v_cvt_pk_bf16_f32 %0, %1, %2" : "=v"(pk0[js*2+1]) : "v"(p0[2]), "v"(p0[3]));
            __asm__("v_cvt_pk_bf16_f32 %0, %1, %2" : "=v"(pk1[js*2])   : "v"(p1[0]), "v"(p1[1]));
            __asm__("v_cvt_pk_bf16_f32 %0, %1, %2" : "=v"(pk1[js*2+1]) : "v"(p1[2]), "v"(p1[3]));
        }

        // T14b: V(next) in flight across P-store + PV (s-acc now dead)
        PREF_V(t2n)

        __syncthreads();  // (C) all waves done reading K0/K1

        // P store (wave-private rows) -> no barrier before readback:
        // same-wave same-address LDS ordering via lgkmcnt (compiler-inserted)
#pragma unroll
        for (int js = 0; js < 4; ++js) {
            *(uint2*)(K0 + myrow + js * 16 + quad * 4) = make_uint2(pk0[js*2], pk0[js*2+1]);
            *(uint2*)(K1 + myrow + js * 16 + quad * 4) = make_uint2(pk1[js*2], pk1[js*2+1]);
        }

        // O += P0.V0 + P1.V1 : A[m=t][k=s] from K0/K1, B[n=d][k=s] from V0/V1
        __builtin_amdgcn_s_setprio(1);
#pragma unroll
        for (int ks = 0; ks < 2; ++ks) {
            s8v p0 = *(const s8v*)(K0 + myrow + ks * 32 + quad * 8);
            s8v p1 = *(const s8v*)(K1 + myrow + ks * 32 + quad * 8);
#pragma unroll
            for (int jd = 0; jd < 4; ++jd) {
                s8v v0_ = *(const s8v*)(V0 + (jd * 16 + col16) * PT + ks * 32 + quad * 8);
                s8v v1_ = *(const s8v*)(V1 + (jd * 16 + col16) * PT + ks * 32 + quad * 8);
                oacc[jd] = __builtin_amdgcn_mfma_f32_16x16x32_bf16(p0, v0_, oacc[jd], 0, 0, 0);
                oacc[jd] = __builtin_amdgcn_mfma_f32_16x16x32_bf16(p1, v1_, oacc[jd], 0, 0, 0);
            }
        }
        __builtin_amdgcn_s_setprio(0);
    }
#undef PREF_K
#undef PREF_V
#undef PREF_M

    // epilogue: reduce row-sum partials (4 s-slots, then cross-quad),
    // normalize and write bf16
    float lr = l4[0] + l4[1] + l4[2] + l4[3];
    lr += __shfl_xor(lr, 16);
    lr += __shfl_xor(lr, 32);
    const float inv = 1.0f / lr;
    float invr[4];
#pragma unroll
    for (int r = 0; r < 4; ++r) invr[r] = __shfl(inv, quad * 4 + r);
#pragma unroll
    for (int r = 0; r < 4; ++r) {
        const int t = t0 + w * 16 + quad * 4 + r;
#pragma unroll
        for (int jd = 0; jd < 4; ++jd)
            O[(size_t)(b_ * TT + t) * EE + h * HDIM + jd * 16 + col16] =
                f2bf(oacc[jd][r] * invr[r]);
    }
}

// ---------------------------------------------------------------------------
extern "C" void kernel_launch(void* const* d_in, const int* in_sizes, int n_in,
                              void* d_out, int out_size, void* d_ws, size_t ws_size,
                              hipStream_t stream)
{
    (void)in_sizes; (void)n_in; (void)out_size; (void)ws_size;

    const float* x    = (const float*)d_in[0];
    const float* mask = (const float*)d_in[1];
    const float* Wq   = (const float*)d_in[2];
    const float* bq   = (const float*)d_in[3];
    const float* Wk   = (const float*)d_in[4];
    const float* bk   = (const float*)d_in[5];
    const float* Wv   = (const float*)d_in[6];
    const float* bv   = (const float*)d_in[7];
    const float* Wo   = (const float*)d_in[8];
    const float* bo   = (const float*)d_in[9];
    float* out = (float*)d_out;

    // workspace carve (ushort units): 42M ushorts = 84 MB
    unsigned short* xb  = (unsigned short*)d_ws;
    unsigned short* wqb = xb  + (size_t)MROWS * EE;          // 4M
    unsigned short* wkb = wqb + (size_t)EE * EE;             // 1M
    unsigned short* wvb = wkb + (size_t)2 * EE * EE;         // 2M
    unsigned short* wob = wvb + (size_t)2 * EE * EE;         // 2M
    unsigned short* mb  = wob + (size_t)EE * EE;             // 1M
    unsigned short* qp  = mb  + (size_t)BB * TT * TT;        // 4M
    unsigned short* kp  = qp  + (size_t)MROWS * EE;          // 4M
    unsigned short* vt  = kp  + (size_t)BB * HH * SS * HDIM; // 8M
    unsigned short* ao  = vt  + (size_t)BB * HH * SS * HDIM; // 8M

    dim3 blk(256);

    // fused fp32->bf16 conversion (x + 4 weights + mask; mask *= log2e)
    cvt6_kernel<<<4096, blk, 0, stream>>>(x, Wq, Wk, Wv, Wo, mask,
                                          xb, wqb, wkb, wvb, wob, mb);
    // fused Q+K projection (Q scaled by SCALE*log2e for exp2-domain softmax)
    gemm_qk_kernel<<<dim3(32, 24), blk, 0, stream>>>(xb, wqb, wkb, bq, bk, qp, kp);
    // V projection computed transposed (A=Wv, W=x) -> V^T [B,H,HD,S]
    gemm_mfma_kernel<2, 0, EE, MROWS><<<dim3(16, 32), blk, 0, stream>>>(
        wvb, xb, bv, vt, 1.0f);
    // attention (split-staggered T14, 3 barriers/iter, setprio, 4 blocks/CU)
    attn_mfma5_kernel<<<dim3(1024), blk, 0, stream>>>(qp, kp, vt, mb, ao);
    // output projection -> fp32 out
    gemm_mfma_kernel<0, 1, EE, EE><<<dim3(32, 8), blk, 0, stream>>>(
        ao, wob, bo, out, 1.0f);
}